// Round 8
// baseline (10528.149 us; speedup 1.0000x reference)
//
#include <hip/hip_runtime.h>
#include <hip/hip_cooperative_groups.h>

namespace cg = cooperative_groups;

typedef unsigned short ushort_t;
typedef unsigned int   uint_t;
using bf16x8 = __attribute__((ext_vector_type(8))) short;
using f32x4  = __attribute__((ext_vector_type(4))) float;
using f32x2  = __attribute__((ext_vector_type(2))) float;
using u32x4  = __attribute__((ext_vector_type(4))) uint_t;

// T=256, B=128, H=512, E=256, IN=512, D=1024, 3H=1536.  ALL float I/O is FP32.

__device__ __forceinline__ float bf2f(ushort_t u) {
  union { uint_t i; float f; } v; v.i = ((uint_t)u) << 16; return v.f;
}
__device__ __forceinline__ ushort_t f2bf(float f) {
  union { float f; uint_t i; } v; v.f = f;
  uint_t r = v.i + 0x7fffu + ((v.i >> 16) & 1u);
  return (ushort_t)(r >> 16);
}
// bit-level scrub: NaN/Inf -> 0
__device__ __forceinline__ float scrub(float x) {
  union { float f; uint_t i; } v; v.f = x;
  return ((v.i & 0x7f800000u) == 0x7f800000u) ? 0.f : x;
}
__device__ __forceinline__ float sclamp(float x) {
  float y = scrub(x);
  return fminf(30.f, fmaxf(-30.f, y));
}
__device__ __forceinline__ float sigm(float x) { return 1.f / (1.f + __expf(-x)); }
__device__ __forceinline__ float tanh_f(float x) {
  float t = __expf(-2.f * fabsf(x));
  float r = (1.f - t) / (1.f + t);
  return x < 0.f ? -r : r;
}
// load 8 f32, convert to bf16x8 (RNE)
__device__ __forceinline__ bf16x8 cvt8(const float* __restrict__ p) {
  f32x4 u0 = *(const f32x4*)p;
  f32x4 u1 = *(const f32x4*)(p + 4);
  bf16x8 r;
  #pragma unroll
  for (int j = 0; j < 4; ++j) { r[j] = (short)f2bf(u0[j]); r[j+4] = (short)f2bf(u1[j]); }
  return r;
}

// ---------------- zero-fill ----------------
__global__ __launch_bounds__(256) void zero_kernel(uint_t* __restrict__ p, int n32) {
  int i = blockIdx.x * 256 + threadIdx.x;
  if (i < n32) p[i] = 0;
}

// ---------------- init h2 (hi|lo packed bf16 split of f32 state), both parities ----------------
__global__ __launch_bounds__(256) void init_kernel(
    const float* __restrict__ state, uint_t* __restrict__ h2) {
  int i = blockIdx.x * 256 + threadIdx.x;   // 0..131071 over (2,128,512)
  float v = state[i];
  ushort_t hi = f2bf(v);
  ushort_t lo = f2bf(v - bf2f(hi));
  uint_t packed = ((uint_t)hi << 16) | (uint_t)lo;
  int dirp = i >> 16;          // 0/1
  int rem  = i & 65535;
  h2[(size_t)(dirp * 2 + 0) * 65536 + rem] = packed;
  h2[(size_t)(dirp * 2 + 1) * 65536 + rem] = packed;
}

// ---------------- transpose W_att (f32 1024x1024) -> WattT bf16 [j][d] ----------------
__global__ __launch_bounds__(256) void transpose_kernel(
    const float* __restrict__ W, ushort_t* __restrict__ WT) {
  __shared__ float tile[32][33];
  int bx = blockIdx.x & 31, by = blockIdx.x >> 5;
  int r0 = by * 32, c0 = bx * 32;
  int tid = threadIdx.x;
  int r = tid >> 3, c4 = (tid & 7) * 4;
  #pragma unroll
  for (int i = 0; i < 4; ++i) tile[r][c4 + i] = W[(size_t)(r0 + r) * 1024 + c0 + c4 + i];
  __syncthreads();
  int jr = tid >> 3, d4 = (tid & 7) * 4;
  #pragma unroll
  for (int i = 0; i < 4; ++i)
    WT[(size_t)(c0 + jr) * 1024 + r0 + d4 + i] = f2bf(tile[d4 + i][jr]);
}

// ---------------- the recurrent kernel (COOPERATIVE, fp32 I/O, split-bf16 MFMA) ----------------
// grid = 256 blocks (blockIdx = wg*4 + dirgroup), 512 threads (8 waves), 1 block/CU.
// dirgroup: 0,1 = fwd groups 0,1 ; 2,3 = bwd groups 0,1. group owns 64 batch rows.
// 64 WGs/dirgroup x 8 h-cols = 512 h-cols. WG owns 24 gate rows; W staged hi+lo in LDS.
// waves 0-3: x-GEMM (inline f32 embedding gather, x=bf16 RNE, 2 products);
// waves 4-7: h-GEMM (h=hi+lo from packed h2, 3 products). grid.sync per step.
__global__ __launch_bounds__(512, 2) void rnn_kernel(
    const int* __restrict__ tim_seq, const int* __restrict__ loc_seq,
    const float* __restrict__ emb_tim, const float* __restrict__ emb_loc,
    uint_t* __restrict__ h2,                // [2dir][2par][128][512] u32 (hi|lo)
    const float* __restrict__ Wih_f, const float* __restrict__ Whh_f,
    const float* __restrict__ bih_f, const float* __restrict__ bhh_f,
    const float* __restrict__ Wih_b, const float* __restrict__ Whh_b,
    const float* __restrict__ bih_b, const float* __restrict__ bhh_b,
    ushort_t* __restrict__ output,          // [256][128][1024] bf16 (intermediate)
    float* __restrict__ state_out)          // d_out + 131072 : [2][128][512] f32
{
  __shared__ __align__(16) ushort_t Wlds[2][2][24 * 512];  // [mat][hi/lo] 98,304 B
  __shared__ float Glds[2][64][26];                        // 13,312 B
  __shared__ float bias_l[6][8];                           //    192 B

  cg::grid_group grid = cg::this_grid();

  const int tid  = threadIdx.x;
  const int lane = tid & 63;
  const int wave = tid >> 6;
  const int bi   = blockIdx.x;
  const int dirgroup = bi & 3;
  const int wg   = bi >> 2;          // 0..63
  const int dir  = dirgroup >> 1;
  const int grp  = dirgroup & 1;
  const int b0   = grp * 64;

  const float* Wih = dir ? Wih_b : Wih_f;
  const float* Whh = dir ? Whh_b : Whh_f;
  const float* bih = dir ? bih_b : bih_f;
  const float* bhh = dir ? bhh_b : bhh_f;

  // stage weight slices (f32 -> hi/lo bf16) into LDS, XOR-swizzled k per gate row
  for (int c = tid; c < 3072; c += 512) {     // 2 matrices * 24 rows * 64 chunks
    int m = c >= 1536 ? 1 : 0;
    int cc = c - m * 1536;
    int gcl = cc >> 6;                        // 0..23 local gate row
    int k8  = (cc & 63) << 3;                 // 0..504
    int grow = (gcl >> 3) * 512 + wg * 8 + (gcl & 7);
    const float* src = (m ? Whh : Wih) + (size_t)grow * 512 + k8;
    f32x4 u0 = *(const f32x4*)src;
    f32x4 u1 = *(const f32x4*)(src + 4);
    bf16x8 hi8, lo8;
    #pragma unroll
    for (int j = 0; j < 8; ++j) {
      float v = j < 4 ? u0[j] : u1[j - 4];
      ushort_t h = f2bf(v);
      hi8[j] = (short)h;
      lo8[j] = (short)f2bf(v - bf2f(h));
    }
    int dst = gcl * 512 + (k8 ^ ((gcl & 7) << 3));
    *(bf16x8*)&Wlds[m][0][dst] = hi8;
    *(bf16x8*)&Wlds[m][1][dst] = lo8;
  }
  if (tid < 48) {
    int m  = tid / 24;                 // 0: bih, 1: bhh
    int gg = (tid % 24) / 8;           // gate r/z/n
    int c  = tid & 7;
    const float* bb = m ? bhh : bih;
    bias_l[m * 3 + gg][c] = bb[gg * 512 + wg * 8 + c];
  }
  __syncthreads();

  const int m     = wave >> 2;         // 0: x-GEMM, 1: h-GEMM
  const int row0  = (wave & 3) * 16;   // row-tile base (0..48)
  const int rlane = lane & 15;
  const int kbase = (lane >> 4) * 8;

  for (int t = 0; t < 256; ++t) {
    const int td  = dir ? (255 - t) : t;
    const int par = t & 1;

    if (m == 0) {
      f32x4 acc[2][2];                 // [ct][Whi/Wlo]
      #pragma unroll
      for (int a = 0; a < 2; ++a)
        #pragma unroll
        for (int b = 0; b < 2; ++b) acc[a][b] = (f32x4){0.f, 0.f, 0.f, 0.f};
      const int arow = b0 + row0 + rlane;
      const int ti = tim_seq[td * 128 + arow];
      const int li = loc_seq[td * 128 + arow];
      const float* tA = emb_tim + (size_t)ti * 256;
      const float* lA = emb_loc + (size_t)li * 256;
      #pragma unroll
      for (int kk = 0; kk < 16; ++kk) {
        int k = kk * 32 + kbase;
        bf16x8 a = (kk < 8) ? cvt8(tA + k) : cvt8(lA + (k - 256));
        #pragma unroll
        for (int ct = 0; ct < 2; ++ct) {
          int gcl = ct * 8 + rlane;    // overlapping tiles: rows 0-15 / 8-23
          int off = gcl * 512 + (k ^ ((gcl & 7) << 3));
          bf16x8 bh = *(const bf16x8*)&Wlds[0][0][off];
          bf16x8 bl = *(const bf16x8*)&Wlds[0][1][off];
          acc[ct][0] = __builtin_amdgcn_mfma_f32_16x16x32_bf16(a, bh, acc[ct][0], 0, 0, 0);
          acc[ct][1] = __builtin_amdgcn_mfma_f32_16x16x32_bf16(a, bl, acc[ct][1], 0, 0, 0);
        }
      }
      #pragma unroll
      for (int ct = 0; ct < 2; ++ct) {
        int gcol = ct * 8 + rlane;
        int r = row0 + (lane >> 4) * 4;
        if (ct == 0 || rlane >= 8) {
          #pragma unroll
          for (int q = 0; q < 4; ++q)
            Glds[0][r + q][gcol] = acc[ct][0][q] + acc[ct][1][q];
        }
      }
    } else {
      f32x4 acc[2][3];                 // [ct][hh, lh, hl]
      #pragma unroll
      for (int a = 0; a < 2; ++a)
        #pragma unroll
        for (int b = 0; b < 3; ++b) acc[a][b] = (f32x4){0.f, 0.f, 0.f, 0.f};
      const uint_t* hrow = h2 + (size_t)(dir * 2 + par) * 65536 +
                           (size_t)(b0 + row0 + rlane) * 512;
      #pragma unroll
      for (int kk = 0; kk < 16; ++kk) {
        int k = kk * 32 + kbase;
        u32x4 w0 = *(const u32x4*)(hrow + k);
        u32x4 w1 = *(const u32x4*)(hrow + k + 4);
        bf16x8 ahi, alo;
        #pragma unroll
        for (int j = 0; j < 4; ++j) {
          ahi[j]   = (short)(w0[j] >> 16); alo[j]   = (short)(w0[j] & 0xffffu);
          ahi[j+4] = (short)(w1[j] >> 16); alo[j+4] = (short)(w1[j] & 0xffffu);
        }
        #pragma unroll
        for (int ct = 0; ct < 2; ++ct) {
          int gcl = ct * 8 + rlane;
          int off = gcl * 512 + (k ^ ((gcl & 7) << 3));
          bf16x8 bh = *(const bf16x8*)&Wlds[1][0][off];
          bf16x8 bl = *(const bf16x8*)&Wlds[1][1][off];
          acc[ct][0] = __builtin_amdgcn_mfma_f32_16x16x32_bf16(ahi, bh, acc[ct][0], 0, 0, 0);
          acc[ct][1] = __builtin_amdgcn_mfma_f32_16x16x32_bf16(alo, bh, acc[ct][1], 0, 0, 0);
          acc[ct][2] = __builtin_amdgcn_mfma_f32_16x16x32_bf16(ahi, bl, acc[ct][2], 0, 0, 0);
        }
      }
      #pragma unroll
      for (int ct = 0; ct < 2; ++ct) {
        int gcol = ct * 8 + rlane;
        int r = row0 + (lane >> 4) * 4;
        if (ct == 0 || rlane >= 8) {
          #pragma unroll
          for (int q = 0; q < 4; ++q)
            Glds[1][r + q][gcol] = acc[ct][0][q] + acc[ct][1][q] + acc[ct][2][q];
        }
      }
    }
    __syncthreads();

    // elementwise: 64 rows x 4 col-pairs = 256 items, one per thread
    if (tid < 256) {
      int row = tid >> 2;
      int cp  = tid & 3;
      int c0  = cp * 2;
      uint_t packed_out = 0;
      float hnv[2];
      size_t hprev = (size_t)(dir * 2 + par) * 65536 + (size_t)(b0 + row) * 512 + wg * 8;
      size_t hnew  = (size_t)(dir * 2 + (par ^ 1)) * 65536 + (size_t)(b0 + row) * 512 + wg * 8;
      #pragma unroll
      for (int j = 0; j < 2; ++j) {
        int c = c0 + j;
        float gxr = sclamp(Glds[0][row][c]      + bias_l[0][c]);
        float gxz = sclamp(Glds[0][row][8 + c]  + bias_l[1][c]);
        float gxn = sclamp(Glds[0][row][16 + c] + bias_l[2][c]);
        float ghr = sclamp(Glds[1][row][c]      + bias_l[3][c]);
        float ghz = sclamp(Glds[1][row][8 + c]  + bias_l[4][c]);
        float ghn = sclamp(Glds[1][row][16 + c] + bias_l[5][c]);
        float r = sigm(gxr + ghr);
        float z = sigm(gxz + ghz);
        float n = tanh_f(gxn + r * ghn);
        uint_t up = h2[hprev + c];
        float hp = bf2f((ushort_t)(up >> 16)) + bf2f((ushort_t)(up & 0xffffu));
        float hn = (1.f - z) * n + z * hp;
        hnv[j] = hn;
        ushort_t hh = f2bf(hn);
        ushort_t hl = f2bf(hn - bf2f(hh));
        h2[hnew + c] = ((uint_t)hh << 16) | (uint_t)hl;
        packed_out |= ((uint_t)hh) << (16 * j);
      }
      *(uint_t*)&output[(size_t)td * 131072 + (size_t)(b0 + row) * 1024 +
                        dir * 512 + wg * 8 + c0] = packed_out;
      if (t == 255) {
        *(f32x2*)&state_out[(size_t)dir * 65536 + (size_t)(b0 + row) * 512 +
                            wg * 8 + c0] = (f32x2){hnv[0], hnv[1]};
      }
    }
    __syncthreads();
    if (t < 255) grid.sync();
  }
}

// ---------------- fused attention scores: scores[b][t] = w_proj . tanh(out @ W_att + b_att) ----------------
__global__ __launch_bounds__(256) void score_kernel(
    const ushort_t* __restrict__ output,   // [32768][1024] bf16
    const ushort_t* __restrict__ WattT,    // [1024][1024] bf16 (j, d)
    const float* __restrict__ b_att,       // [1024] f32
    const float* __restrict__ w_proj,      // [1024] f32
    float* __restrict__ scores)            // [128][256]
{
  __shared__ __align__(16) ushort_t bst[2][128][72];
  __shared__ float scl[128];
  const int tid = threadIdx.x, lane = tid & 63, wave = tid >> 6;
  const int tb0 = blockIdx.x * 128;
  if (tid < 128) scl[tid] = 0.f;
  __syncthreads();

  const int rlane = lane & 15;
  const int kbase = (lane >> 4) * 8;
  const int sjrow = tid >> 2;
  const int sq8   = (tid & 3) * 8;

  for (int jc = 0; jc < 8; ++jc) {
    f32x4 acc[2][8];
    #pragma unroll
    for (int rt = 0; rt < 2; ++rt)
      #pragma unroll
      for (int ct = 0; ct < 8; ++ct) acc[rt][ct] = (f32x4){0.f, 0.f, 0.f, 0.f};

    {
      const size_t base = (size_t)(jc * 128) * 1024 + sq8;
      *(bf16x8*)&bst[0][sjrow][sq8] = *(const bf16x8*)(WattT + base + (size_t)sjrow * 1024);
      *(bf16x8*)&bst[0][sjrow + 64][sq8] = *(const bf16x8*)(WattT + base + (size_t)(sjrow + 64) * 1024);
    }
    __syncthreads();

    for (int kc = 0; kc < 32; ++kc) {
      if (kc < 31) {
        const size_t base = (size_t)(jc * 128) * 1024 + (size_t)(kc + 1) * 32 + sq8;
        *(bf16x8*)&bst[(kc + 1) & 1][sjrow][sq8] =
            *(const bf16x8*)(WattT + base + (size_t)sjrow * 1024);
        *(bf16x8*)&bst[(kc + 1) & 1][sjrow + 64][sq8] =
            *(const bf16x8*)(WattT + base + (size_t)(sjrow + 64) * 1024);
      }
      int r0 = wave * 32 + rlane;
      int k = kc * 32 + kbase;
      bf16x8 a0 = *(const bf16x8*)(output + (size_t)(tb0 + r0) * 1024 + k);
      bf16x8 a1 = *(const bf16x8*)(output + (size_t)(tb0 + r0 + 16) * 1024 + k);
      int buf = kc & 1;
      #pragma unroll
      for (int ct = 0; ct < 8; ++ct) {
        bf16x8 b = *(const bf16x8*)&bst[buf][ct * 16 + rlane][kbase];
        acc[0][ct] = __builtin_amdgcn_mfma_f32_16x16x32_bf16(a0, b, acc[0][ct], 0, 0, 0);
        acc[1][ct] = __builtin_amdgcn_mfma_f32_16x16x32_bf16(a1, b, acc[1][ct], 0, 0, 0);
      }
      __syncthreads();
    }

    float s[2][4] = {{0.f, 0.f, 0.f, 0.f}, {0.f, 0.f, 0.f, 0.f}};
    #pragma unroll
    for (int ct = 0; ct < 8; ++ct) {
      int j = jc * 128 + ct * 16 + rlane;
      float bv = b_att[j];
      float wv = w_proj[j];
      #pragma unroll
      for (int rt = 0; rt < 2; ++rt)
        #pragma unroll
        for (int q = 0; q < 4; ++q)
          s[rt][q] += tanh_f(sclamp(acc[rt][ct][q] + bv)) * wv;
    }
    #pragma unroll
    for (int rt = 0; rt < 2; ++rt)
      #pragma unroll
      for (int q = 0; q < 4; ++q) {
        float v = s[rt][q];
        v += __shfl_xor(v, 1, 64);
        v += __shfl_xor(v, 2, 64);
        v += __shfl_xor(v, 4, 64);
        v += __shfl_xor(v, 8, 64);
        if ((lane & 15) == 0)
          scl[wave * 32 + rt * 16 + (lane >> 4) * 4 + q] += v;
      }
  }
  __syncthreads();
  if (tid < 128) {
    int tb = tb0 + tid;
    scores[(size_t)(tb & 127) * 256 + (tb >> 7)] = scrub(scl[tid]);
  }
}

// ---------------- softmax over t per batch row (f32 out) ----------------
__global__ __launch_bounds__(256) void softmax_kernel(
    const float* __restrict__ scores, float* __restrict__ attn_out) {
  __shared__ float red[4];
  int b = blockIdx.x, tid = threadIdx.x, lane = tid & 63, wave = tid >> 6;
  float v = scrub(scores[(size_t)b * 256 + tid]);
  float mx = v;
  #pragma unroll
  for (int o = 1; o < 64; o <<= 1) mx = fmaxf(mx, __shfl_xor(mx, o, 64));
  if (lane == 0) red[wave] = mx;
  __syncthreads();
  mx = fmaxf(fmaxf(red[0], red[1]), fmaxf(red[2], red[3]));
  float e = __expf(v - mx);
  float s = e;
  #pragma unroll
  for (int o = 1; o < 64; o <<= 1) s += __shfl_xor(s, o, 64);
  __syncthreads();
  if (lane == 0) red[wave] = s;
  __syncthreads();
  s = red[0] + red[1] + red[2] + red[3];
  attn_out[(size_t)b * 256 + tid] = e / s;
}

// ---------------- pooled[b][d] = sum_t attn[b][t]*output[t][b][d] (f32 out) ----------------
__global__ __launch_bounds__(256) void pool_kernel(
    const float* __restrict__ attnw, const ushort_t* __restrict__ output,
    float* __restrict__ pooled) {
  __shared__ float at[256];
  int bi = blockIdx.x;
  int b = bi >> 1, half = bi & 1;
  int tid = threadIdx.x;
  at[tid] = scrub(attnw[(size_t)b * 256 + tid]);
  __syncthreads();
  int d0 = half * 512 + tid * 2;
  float a0 = 0.f, a1 = 0.f;
  for (int t = 0; t < 256; ++t) {
    uint_t u = *(const uint_t*)&output[(size_t)t * 131072 + (size_t)b * 1024 + d0];
    float w = at[t];
    a0 += w * scrub(bf2f((ushort_t)(u & 0xffffu)));
    a1 += w * scrub(bf2f((ushort_t)(u >> 16)));
  }
  *(f32x2*)&pooled[(size_t)b * 1024 + d0] = (f32x2){a0, a1};
}

extern "C" void kernel_launch(void* const* d_in, const int* in_sizes, int n_in,
                              void* d_out, int out_size, void* d_ws, size_t ws_size,
                              hipStream_t stream) {
  (void)in_sizes; (void)n_in; (void)out_size;
  const int*   tim_seq = (const int*)d_in[0];
  const int*   loc_seq = (const int*)d_in[1];
  const float* state   = (const float*)d_in[2];
  const float* emb_tim = (const float*)d_in[3];
  const float* emb_loc = (const float*)d_in[4];
  const float* Wih_f   = (const float*)d_in[5];
  const float* Whh_f   = (const float*)d_in[6];
  const float* bih_f   = (const float*)d_in[7];
  const float* bhh_f   = (const float*)d_in[8];
  const float* Wih_b   = (const float*)d_in[9];
  const float* Whh_b   = (const float*)d_in[10];
  const float* bih_b   = (const float*)d_in[11];
  const float* bhh_b   = (const float*)d_in[12];
  const float* W_att   = (const float*)d_in[13];
  const float* b_att   = (const float*)d_in[14];
  const float* w_proj  = (const float*)d_in[15];
  float* out = (float*)d_out;   // [pooled 131072][state 131072][attn 32768] f32

  // Workspace layout (~70.5 MB; previously verified >= 71.3 MB available)
  char* ws = (char*)d_ws;
  float*    scores = (float*)   (ws);                   //   131,072 B
  uint_t*   h2     = (uint_t*)  (ws + 131072);          // 1,048,576 B
  ushort_t* WattT  = (ushort_t*)(ws + 1179648);         // 2,097,152 B
  ushort_t* output = (ushort_t*)(ws + 3276800);         // 67,108,864 B
  const size_t NEED = 3276800 + 67108864;
  if (ws_size < NEED) return;

  zero_kernel<<<3200, 256, 0, stream>>>((uint_t*)ws, 819200);         // front 3.2MB
  zero_kernel<<<16384, 256, 0, stream>>>((uint_t*)output, 16777216);  // output 64MB

  init_kernel<<<512, 256, 0, stream>>>(state, h2);
  transpose_kernel<<<1024, 256, 0, stream>>>(W_att, WattT);

  float* state_out = out + 131072;
  void* args[] = {
    (void*)&tim_seq, (void*)&loc_seq, (void*)&emb_tim, (void*)&emb_loc,
    (void*)&h2,
    (void*)&Wih_f, (void*)&Whh_f, (void*)&bih_f, (void*)&bhh_f,
    (void*)&Wih_b, (void*)&Whh_b, (void*)&bih_b, (void*)&bhh_b,
    (void*)&output, (void*)&state_out
  };
  hipLaunchCooperativeKernel(reinterpret_cast<void*>(rnn_kernel),
                             dim3(256), dim3(512), args, 0, stream);

  score_kernel<<<256, 256, 0, stream>>>(output, WattT, b_att, w_proj, scores);
  softmax_kernel<<<128, 256, 0, stream>>>(scores, out + 262144);
  pool_kernel<<<256, 256, 0, stream>>>(out + 262144, output, out);
}

// Round 9
// 10262.460 us; speedup vs baseline: 1.0259x; 1.0259x over previous
//
#include <hip/hip_runtime.h>

typedef unsigned short ushort_t;
typedef unsigned int   uint_t;
typedef unsigned long long u64;
using bf16x8 = __attribute__((ext_vector_type(8))) short;
using f32x4  = __attribute__((ext_vector_type(4))) float;
using f32x2  = __attribute__((ext_vector_type(2))) float;
using u32x4  = __attribute__((ext_vector_type(4))) uint_t;

// T=256, B=128, H=512, E=256, IN=512, D=1024, 3H=1536.  ALL float I/O is FP32.

__device__ __forceinline__ float bf2f(ushort_t u) {
  union { uint_t i; float f; } v; v.i = ((uint_t)u) << 16; return v.f;
}
__device__ __forceinline__ ushort_t f2bf(float f) {
  union { float f; uint_t i; } v; v.f = f;
  uint_t r = v.i + 0x7fffu + ((v.i >> 16) & 1u);
  return (ushort_t)(r >> 16);
}
// bit-level scrub: NaN/Inf -> 0
__device__ __forceinline__ float scrub(float x) {
  union { float f; uint_t i; } v; v.f = x;
  return ((v.i & 0x7f800000u) == 0x7f800000u) ? 0.f : x;
}
__device__ __forceinline__ float sclamp(float x) {
  float y = scrub(x);
  return fminf(30.f, fmaxf(-30.f, y));
}
__device__ __forceinline__ float sigm(float x) { return 1.f / (1.f + __expf(-x)); }
__device__ __forceinline__ float tanh_f(float x) {
  float t = __expf(-2.f * fabsf(x));
  float r = (1.f - t) / (1.f + t);
  return x < 0.f ? -r : r;
}
// load 8 f32, convert to bf16x8 (RNE)
__device__ __forceinline__ bf16x8 cvt8(const float* __restrict__ p) {
  f32x4 u0 = *(const f32x4*)p;
  f32x4 u1 = *(const f32x4*)(p + 4);
  bf16x8 r;
  #pragma unroll
  for (int j = 0; j < 4; ++j) { r[j] = (short)f2bf(u0[j]); r[j+4] = (short)f2bf(u1[j]); }
  return r;
}

// ---------------- zero-fill ----------------
__global__ __launch_bounds__(256) void zero_kernel(uint_t* __restrict__ p, int n32) {
  int i = blockIdx.x * 256 + threadIdx.x;
  if (i < n32) p[i] = 0;
}

// ---------------- init h2 (hi|lo packed bf16 split of f32 state), both parities ----------------
__global__ __launch_bounds__(256) void init_kernel(
    const float* __restrict__ state, uint_t* __restrict__ h2) {
  int i = blockIdx.x * 256 + threadIdx.x;   // 0..131071 over (2,128,512)
  float v = state[i];
  ushort_t hi = f2bf(v);
  ushort_t lo = f2bf(v - bf2f(hi));
  uint_t packed = ((uint_t)hi << 16) | (uint_t)lo;
  int dirp = i >> 16;          // 0/1
  int rem  = i & 65535;
  h2[(size_t)(dirp * 2 + 0) * 65536 + rem] = packed;
  h2[(size_t)(dirp * 2 + 1) * 65536 + rem] = packed;
}

// ---------------- transpose W_att (f32 1024x1024) -> WattT bf16 [j][d] ----------------
__global__ __launch_bounds__(256) void transpose_kernel(
    const float* __restrict__ W, ushort_t* __restrict__ WT) {
  __shared__ float tile[32][33];
  int bx = blockIdx.x & 31, by = blockIdx.x >> 5;
  int r0 = by * 32, c0 = bx * 32;
  int tid = threadIdx.x;
  int r = tid >> 3, c4 = (tid & 7) * 4;
  #pragma unroll
  for (int i = 0; i < 4; ++i) tile[r][c4 + i] = W[(size_t)(r0 + r) * 1024 + c0 + c4 + i];
  __syncthreads();
  int jr = tid >> 3, d4 = (tid & 7) * 4;
  #pragma unroll
  for (int i = 0; i < 4; ++i)
    WT[(size_t)(c0 + jr) * 1024 + r0 + d4 + i] = f2bf(tile[d4 + i][jr]);
}

// ---------------- the recurrent kernel (flag-ring sync, fp32 I/O, split-bf16 MFMA) ----------------
// grid = 256 blocks (blockIdx = wg*4 + dirgroup), 512 threads (8 waves), 1 block/CU
// (112KB LDS forces 1/CU; 256 blocks = 256 CUs -> co-resident, spin-safe).
// dirgroup: 0,1 = fwd groups 0,1 ; 2,3 = bwd groups 0,1. group owns 64 batch rows.
// 64 WGs/dirgroup x 8 h-cols = 512 h-cols. WG owns 24 gate rows; W staged hi+lo in LDS.
// waves 0-3: x-GEMM (no dependency); waves 4-7: spin on 64 flags >= t, acquire fence,
// h-GEMM (agent-scope atomic h reads). h2 parity double-buffer: read t&1, write (t&1)^1.
// Flag release after __syncthreads (drains vmcnt) -> h2 stores visible before flag.
__global__ __launch_bounds__(512, 2) void rnn_kernel(
    const int* __restrict__ tim_seq, const int* __restrict__ loc_seq,
    const float* __restrict__ emb_tim, const float* __restrict__ emb_loc,
    uint_t* __restrict__ h2,                // [2dir][2par][128][512] u32 (hi|lo)
    const float* __restrict__ Wih_f, const float* __restrict__ Whh_f,
    const float* __restrict__ bih_f, const float* __restrict__ bhh_f,
    const float* __restrict__ Wih_b, const float* __restrict__ Whh_b,
    const float* __restrict__ bih_b, const float* __restrict__ bhh_b,
    ushort_t* __restrict__ output,          // [256][128][1024] bf16 (intermediate)
    float* __restrict__ state_out,          // d_out + 131072 : [2][128][512] f32
    uint_t* __restrict__ flags)             // [4][64]
{
  __shared__ __align__(16) ushort_t Wlds[2][2][24 * 512];  // [mat][hi/lo] 98,304 B
  __shared__ float Glds[2][64][27];                        // 13,824 B (odd stride: all banks)
  __shared__ float bias_l[6][8];                           //    192 B

  const int tid  = threadIdx.x;
  const int lane = tid & 63;
  const int wave = tid >> 6;
  const int bi   = blockIdx.x;
  const int dirgroup = bi & 3;
  const int wg   = bi >> 2;          // 0..63
  const int dir  = dirgroup >> 1;
  const int grp  = dirgroup & 1;
  const int b0   = grp * 64;
  const uint_t fb = (uint_t)dirgroup * 64;

  const float* Wih = dir ? Wih_b : Wih_f;
  const float* Whh = dir ? Whh_b : Whh_f;
  const float* bih = dir ? bih_b : bih_f;
  const float* bhh = dir ? bhh_b : bhh_f;

  // stage weight slices (f32 -> hi/lo bf16) into LDS, XOR-swizzled k per gate row
  for (int c = tid; c < 3072; c += 512) {     // 2 matrices * 24 rows * 64 chunks
    int m = c >= 1536 ? 1 : 0;
    int cc = c - m * 1536;
    int gcl = cc >> 6;                        // 0..23 local gate row
    int k8  = (cc & 63) << 3;                 // 0..504
    int grow = (gcl >> 3) * 512 + wg * 8 + (gcl & 7);
    const float* src = (m ? Whh : Wih) + (size_t)grow * 512 + k8;
    f32x4 u0 = *(const f32x4*)src;
    f32x4 u1 = *(const f32x4*)(src + 4);
    bf16x8 hi8, lo8;
    #pragma unroll
    for (int j = 0; j < 8; ++j) {
      float v = j < 4 ? u0[j] : u1[j - 4];
      ushort_t h = f2bf(v);
      hi8[j] = (short)h;
      lo8[j] = (short)f2bf(v - bf2f(h));
    }
    int dst = gcl * 512 + (k8 ^ ((gcl & 7) << 3));
    *(bf16x8*)&Wlds[m][0][dst] = hi8;
    *(bf16x8*)&Wlds[m][1][dst] = lo8;
  }
  if (tid < 48) {
    int m  = tid / 24;                 // 0: bih, 1: bhh
    int gg = (tid % 24) / 8;           // gate r/z/n
    int c  = tid & 7;
    const float* bb = m ? bhh : bih;
    bias_l[m * 3 + gg][c] = bb[gg * 512 + wg * 8 + c];
  }
  __syncthreads();

  const int m     = wave >> 2;         // 0: x-GEMM, 1: h-GEMM
  const int row0  = (wave & 3) * 16;   // row-tile base (0..48)
  const int rlane = lane & 15;
  const int kbase = (lane >> 4) * 8;

  for (int t = 0; t < 256; ++t) {
    const int td  = dir ? (255 - t) : t;
    const int par = t & 1;

    if (m == 0) {
      f32x4 acc[2][2];                 // [ct][Whi/Wlo]
      #pragma unroll
      for (int a = 0; a < 2; ++a)
        #pragma unroll
        for (int b = 0; b < 2; ++b) acc[a][b] = (f32x4){0.f, 0.f, 0.f, 0.f};
      const int arow = b0 + row0 + rlane;
      const int ti = tim_seq[td * 128 + arow];
      const int li = loc_seq[td * 128 + arow];
      const float* tA = emb_tim + (size_t)ti * 256;
      const float* lA = emb_loc + (size_t)li * 256;
      #pragma unroll
      for (int kk = 0; kk < 16; ++kk) {
        int k = kk * 32 + kbase;
        bf16x8 a = (kk < 8) ? cvt8(tA + k) : cvt8(lA + (k - 256));
        #pragma unroll
        for (int ct = 0; ct < 2; ++ct) {
          int gcl = ct * 8 + rlane;    // overlapping tiles: rows 0-15 / 8-23
          int off = gcl * 512 + (k ^ ((gcl & 7) << 3));
          bf16x8 bh = *(const bf16x8*)&Wlds[0][0][off];
          bf16x8 bl = *(const bf16x8*)&Wlds[0][1][off];
          acc[ct][0] = __builtin_amdgcn_mfma_f32_16x16x32_bf16(a, bh, acc[ct][0], 0, 0, 0);
          acc[ct][1] = __builtin_amdgcn_mfma_f32_16x16x32_bf16(a, bl, acc[ct][1], 0, 0, 0);
        }
      }
      #pragma unroll
      for (int ct = 0; ct < 2; ++ct) {
        int gcol = ct * 8 + rlane;
        int r = row0 + (lane >> 4) * 4;
        if (ct == 0 || rlane >= 8) {
          #pragma unroll
          for (int q = 0; q < 4; ++q)
            Glds[0][r + q][gcol] = acc[ct][0][q] + acc[ct][1][q];
        }
      }
    } else {
      // wait for all 64 producer WGs of this dirgroup to reach step t
      while (__hip_atomic_load(&flags[fb + lane], __ATOMIC_RELAXED,
                               __HIP_MEMORY_SCOPE_AGENT) < (uint_t)t) {
        __builtin_amdgcn_s_sleep(2);
      }
      __threadfence();  // acquire: invalidate stale caches before h reads

      f32x4 acc[2][3];                 // [ct][hh, lh, hl]
      #pragma unroll
      for (int a = 0; a < 2; ++a)
        #pragma unroll
        for (int b = 0; b < 3; ++b) acc[a][b] = (f32x4){0.f, 0.f, 0.f, 0.f};
      const u64* hrow = (const u64*)(h2 + (size_t)(dir * 2 + par) * 65536 +
                                     (size_t)(b0 + row0 + rlane) * 512);
      #pragma unroll
      for (int kk = 0; kk < 16; ++kk) {
        int k = kk * 32 + kbase;       // u32 index; /2 -> u64 index
        u64 q0 = __hip_atomic_load(hrow + (k >> 1),     __ATOMIC_RELAXED,
                                   __HIP_MEMORY_SCOPE_AGENT);
        u64 q1 = __hip_atomic_load(hrow + (k >> 1) + 1, __ATOMIC_RELAXED,
                                   __HIP_MEMORY_SCOPE_AGENT);
        u64 q2 = __hip_atomic_load(hrow + (k >> 1) + 2, __ATOMIC_RELAXED,
                                   __HIP_MEMORY_SCOPE_AGENT);
        u64 q3 = __hip_atomic_load(hrow + (k >> 1) + 3, __ATOMIC_RELAXED,
                                   __HIP_MEMORY_SCOPE_AGENT);
        uint_t w[8] = { (uint_t)q0, (uint_t)(q0 >> 32), (uint_t)q1, (uint_t)(q1 >> 32),
                        (uint_t)q2, (uint_t)(q2 >> 32), (uint_t)q3, (uint_t)(q3 >> 32) };
        bf16x8 ahi, alo;
        #pragma unroll
        for (int j = 0; j < 8; ++j) {
          ahi[j] = (short)(w[j] >> 16);
          alo[j] = (short)(w[j] & 0xffffu);
        }
        #pragma unroll
        for (int ct = 0; ct < 2; ++ct) {
          int gcl = ct * 8 + rlane;
          int off = gcl * 512 + (k ^ ((gcl & 7) << 3));
          bf16x8 bh = *(const bf16x8*)&Wlds[1][0][off];
          bf16x8 bl = *(const bf16x8*)&Wlds[1][1][off];
          acc[ct][0] = __builtin_amdgcn_mfma_f32_16x16x32_bf16(ahi, bh, acc[ct][0], 0, 0, 0);
          acc[ct][1] = __builtin_amdgcn_mfma_f32_16x16x32_bf16(alo, bh, acc[ct][1], 0, 0, 0);
          acc[ct][2] = __builtin_amdgcn_mfma_f32_16x16x32_bf16(ahi, bl, acc[ct][2], 0, 0, 0);
        }
      }
      #pragma unroll
      for (int ct = 0; ct < 2; ++ct) {
        int gcol = ct * 8 + rlane;
        int r = row0 + (lane >> 4) * 4;
        if (ct == 0 || rlane >= 8) {
          #pragma unroll
          for (int q = 0; q < 4; ++q)
            Glds[1][r + q][gcol] = acc[ct][0][q] + acc[ct][1][q] + acc[ct][2][q];
        }
      }
    }
    __syncthreads();

    // elementwise: 64 rows x 4 col-pairs = 256 items, one per thread
    if (tid < 256) {
      int row = tid >> 2;
      int cp  = tid & 3;
      int c0  = cp * 2;
      uint_t packed_out = 0;
      float hnv[2];
      size_t hprev = (size_t)(dir * 2 + par) * 65536 + (size_t)(b0 + row) * 512 + wg * 8;
      size_t hnew  = (size_t)(dir * 2 + (par ^ 1)) * 65536 + (size_t)(b0 + row) * 512 + wg * 8;
      #pragma unroll
      for (int j = 0; j < 2; ++j) {
        int c = c0 + j;
        float gxr = sclamp(Glds[0][row][c]      + bias_l[0][c]);
        float gxz = sclamp(Glds[0][row][8 + c]  + bias_l[1][c]);
        float gxn = sclamp(Glds[0][row][16 + c] + bias_l[2][c]);
        float ghr = sclamp(Glds[1][row][c]      + bias_l[3][c]);
        float ghz = sclamp(Glds[1][row][8 + c]  + bias_l[4][c]);
        float ghn = sclamp(Glds[1][row][16 + c] + bias_l[5][c]);
        float r = sigm(gxr + ghr);
        float z = sigm(gxz + ghz);
        float n = tanh_f(gxn + r * ghn);
        uint_t up = h2[hprev + c];     // own-block write -> L1 write-through safe
        float hp = bf2f((ushort_t)(up >> 16)) + bf2f((ushort_t)(up & 0xffffu));
        float hn = (1.f - z) * n + z * hp;
        hnv[j] = hn;
        ushort_t hh = f2bf(hn);
        ushort_t hl = f2bf(hn - bf2f(hh));
        __hip_atomic_store(&h2[hnew + c], ((uint_t)hh << 16) | (uint_t)hl,
                           __ATOMIC_RELAXED, __HIP_MEMORY_SCOPE_AGENT);
        packed_out |= ((uint_t)hh) << (16 * j);
      }
      *(uint_t*)&output[(size_t)td * 131072 + (size_t)(b0 + row) * 1024 +
                        dir * 512 + wg * 8 + c0] = packed_out;
      if (t == 255) {
        *(f32x2*)&state_out[(size_t)dir * 65536 + (size_t)(b0 + row) * 512 +
                            wg * 8 + c0] = (f32x2){hnv[0], hnv[1]};
      }
    }
    __syncthreads();   // drains each thread's vmcnt: h2 stores committed
    if (t < 255 && tid == 0) {
      __hip_atomic_store(&flags[fb + wg], (uint_t)(t + 1), __ATOMIC_RELEASE,
                         __HIP_MEMORY_SCOPE_AGENT);
    }
  }
}

// ---------------- fused attention scores: scores[b][t] = w_proj . tanh(out @ W_att + b_att) ----------------
__global__ __launch_bounds__(256) void score_kernel(
    const ushort_t* __restrict__ output,   // [32768][1024] bf16
    const ushort_t* __restrict__ WattT,    // [1024][1024] bf16 (j, d)
    const float* __restrict__ b_att,       // [1024] f32
    const float* __restrict__ w_proj,      // [1024] f32
    float* __restrict__ scores)            // [128][256]
{
  __shared__ __align__(16) ushort_t bst[2][128][72];
  __shared__ float scl[128];
  const int tid = threadIdx.x, lane = tid & 63, wave = tid >> 6;
  const int tb0 = blockIdx.x * 128;
  if (tid < 128) scl[tid] = 0.f;
  __syncthreads();

  const int rlane = lane & 15;
  const int kbase = (lane >> 4) * 8;
  const int sjrow = tid >> 2;
  const int sq8   = (tid & 3) * 8;

  for (int jc = 0; jc < 8; ++jc) {
    f32x4 acc[2][8];
    #pragma unroll
    for (int rt = 0; rt < 2; ++rt)
      #pragma unroll
      for (int ct = 0; ct < 8; ++ct) acc[rt][ct] = (f32x4){0.f, 0.f, 0.f, 0.f};

    {
      const size_t base = (size_t)(jc * 128) * 1024 + sq8;
      *(bf16x8*)&bst[0][sjrow][sq8] = *(const bf16x8*)(WattT + base + (size_t)sjrow * 1024);
      *(bf16x8*)&bst[0][sjrow + 64][sq8] = *(const bf16x8*)(WattT + base + (size_t)(sjrow + 64) * 1024);
    }
    __syncthreads();

    for (int kc = 0; kc < 32; ++kc) {
      if (kc < 31) {
        const size_t base = (size_t)(jc * 128) * 1024 + (size_t)(kc + 1) * 32 + sq8;
        *(bf16x8*)&bst[(kc + 1) & 1][sjrow][sq8] =
            *(const bf16x8*)(WattT + base + (size_t)sjrow * 1024);
        *(bf16x8*)&bst[(kc + 1) & 1][sjrow + 64][sq8] =
            *(const bf16x8*)(WattT + base + (size_t)(sjrow + 64) * 1024);
      }
      int r0 = wave * 32 + rlane;
      int k = kc * 32 + kbase;
      bf16x8 a0 = *(const bf16x8*)(output + (size_t)(tb0 + r0) * 1024 + k);
      bf16x8 a1 = *(const bf16x8*)(output + (size_t)(tb0 + r0 + 16) * 1024 + k);
      int buf = kc & 1;
      #pragma unroll
      for (int ct = 0; ct < 8; ++ct) {
        bf16x8 b = *(const bf16x8*)&bst[buf][ct * 16 + rlane][kbase];
        acc[0][ct] = __builtin_amdgcn_mfma_f32_16x16x32_bf16(a0, b, acc[0][ct], 0, 0, 0);
        acc[1][ct] = __builtin_amdgcn_mfma_f32_16x16x32_bf16(a1, b, acc[1][ct], 0, 0, 0);
      }
      __syncthreads();
    }

    float s[2][4] = {{0.f, 0.f, 0.f, 0.f}, {0.f, 0.f, 0.f, 0.f}};
    #pragma unroll
    for (int ct = 0; ct < 8; ++ct) {
      int j = jc * 128 + ct * 16 + rlane;
      float bv = b_att[j];
      float wv = w_proj[j];
      #pragma unroll
      for (int rt = 0; rt < 2; ++rt)
        #pragma unroll
        for (int q = 0; q < 4; ++q)
          s[rt][q] += tanh_f(sclamp(acc[rt][ct][q] + bv)) * wv;
    }
    #pragma unroll
    for (int rt = 0; rt < 2; ++rt)
      #pragma unroll
      for (int q = 0; q < 4; ++q) {
        float v = s[rt][q];
        v += __shfl_xor(v, 1, 64);
        v += __shfl_xor(v, 2, 64);
        v += __shfl_xor(v, 4, 64);
        v += __shfl_xor(v, 8, 64);
        if ((lane & 15) == 0)
          scl[wave * 32 + rt * 16 + (lane >> 4) * 4 + q] += v;
      }
  }
  __syncthreads();
  if (tid < 128) {
    int tb = tb0 + tid;
    scores[(size_t)(tb & 127) * 256 + (tb >> 7)] = scrub(scl[tid]);
  }
}

// ---------------- softmax over t per batch row (f32 out) ----------------
__global__ __launch_bounds__(256) void softmax_kernel(
    const float* __restrict__ scores, float* __restrict__ attn_out) {
  __shared__ float red[4];
  int b = blockIdx.x, tid = threadIdx.x, lane = tid & 63, wave = tid >> 6;
  float v = scrub(scores[(size_t)b * 256 + tid]);
  float mx = v;
  #pragma unroll
  for (int o = 1; o < 64; o <<= 1) mx = fmaxf(mx, __shfl_xor(mx, o, 64));
  if (lane == 0) red[wave] = mx;
  __syncthreads();
  mx = fmaxf(fmaxf(red[0], red[1]), fmaxf(red[2], red[3]));
  float e = __expf(v - mx);
  float s = e;
  #pragma unroll
  for (int o = 1; o < 64; o <<= 1) s += __shfl_xor(s, o, 64);
  __syncthreads();
  if (lane == 0) red[wave] = s;
  __syncthreads();
  s = red[0] + red[1] + red[2] + red[3];
  attn_out[(size_t)b * 256 + tid] = e / s;
}

// ---------------- pooled[b][d] = sum_t attn[b][t]*output[t][b][d] (f32 out) ----------------
__global__ __launch_bounds__(256) void pool_kernel(
    const float* __restrict__ attnw, const ushort_t* __restrict__ output,
    float* __restrict__ pooled) {
  __shared__ float at[256];
  int bi = blockIdx.x;
  int b = bi >> 1, half = bi & 1;
  int tid = threadIdx.x;
  at[tid] = scrub(attnw[(size_t)b * 256 + tid]);
  __syncthreads();
  int d0 = half * 512 + tid * 2;
  float a0 = 0.f, a1 = 0.f;
  for (int t = 0; t < 256; ++t) {
    uint_t u = *(const uint_t*)&output[(size_t)t * 131072 + (size_t)b * 1024 + d0];
    float w = at[t];
    a0 += w * scrub(bf2f((ushort_t)(u & 0xffffu)));
    a1 += w * scrub(bf2f((ushort_t)(u >> 16)));
  }
  *(f32x2*)&pooled[(size_t)b * 1024 + d0] = (f32x2){a0, a1};
}

extern "C" void kernel_launch(void* const* d_in, const int* in_sizes, int n_in,
                              void* d_out, int out_size, void* d_ws, size_t ws_size,
                              hipStream_t stream) {
  (void)in_sizes; (void)n_in; (void)out_size;
  const int*   tim_seq = (const int*)d_in[0];
  const int*   loc_seq = (const int*)d_in[1];
  const float* state   = (const float*)d_in[2];
  const float* emb_tim = (const float*)d_in[3];
  const float* emb_loc = (const float*)d_in[4];
  const float* Wih_f   = (const float*)d_in[5];
  const float* Whh_f   = (const float*)d_in[6];
  const float* bih_f   = (const float*)d_in[7];
  const float* bhh_f   = (const float*)d_in[8];
  const float* Wih_b   = (const float*)d_in[9];
  const float* Whh_b   = (const float*)d_in[10];
  const float* bih_b   = (const float*)d_in[11];
  const float* bhh_b   = (const float*)d_in[12];
  const float* W_att   = (const float*)d_in[13];
  const float* b_att   = (const float*)d_in[14];
  const float* w_proj  = (const float*)d_in[15];
  float* out = (float*)d_out;   // [pooled 131072][state 131072][attn 32768] f32

  // Workspace layout (~70.5 MB; verified available)
  char* ws = (char*)d_ws;
  float*    scores = (float*)   (ws);                   //   131,072 B
  uint_t*   flags  = (uint_t*)  (ws + 131072);          //     1,024 B
  uint_t*   h2     = (uint_t*)  (ws + 132096);          // 1,048,576 B
  ushort_t* WattT  = (ushort_t*)(ws + 1180672);         // 2,097,152 B
  ushort_t* output = (ushort_t*)(ws + 3277824);         // 67,108,864 B
  const size_t NEED = 3277824 + 67108864;
  if (ws_size < NEED) return;

  zero_kernel<<<3200, 256, 0, stream>>>((uint_t*)ws, 819200);         // front 3.2MB (incl flags)
  zero_kernel<<<16384, 256, 0, stream>>>((uint_t*)output, 16777216);  // output 64MB

  init_kernel<<<512, 256, 0, stream>>>(state, h2);
  transpose_kernel<<<1024, 256, 0, stream>>>(W_att, WattT);

  rnn_kernel<<<256, 512, 0, stream>>>(tim_seq, loc_seq, emb_tim, emb_loc,
                                      h2,
                                      Wih_f, Whh_f, bih_f, bhh_f,
                                      Wih_b, Whh_b, bih_b, bhh_b,
                                      output, out + 131072, flags);

  score_kernel<<<256, 256, 0, stream>>>(output, WattT, b_att, w_proj, scores);
  softmax_kernel<<<128, 256, 0, stream>>>(scores, out + 262144);
  pool_kernel<<<256, 256, 0, stream>>>(out + 262144, output, out);
}

// Round 10
// 4475.666 us; speedup vs baseline: 2.3523x; 2.2929x over previous
//
#include <hip/hip_runtime.h>

typedef unsigned short ushort_t;
typedef unsigned int   uint_t;
typedef unsigned long long u64;
using bf16x8 = __attribute__((ext_vector_type(8))) short;
using f32x4  = __attribute__((ext_vector_type(4))) float;
using f32x2  = __attribute__((ext_vector_type(2))) float;

// T=256, B=128, H=512, E=256, IN=512, D=1024, 3H=1536.  ALL float I/O is FP32.

__device__ __forceinline__ float bf2f(ushort_t u) {
  union { uint_t i; float f; } v; v.i = ((uint_t)u) << 16; return v.f;
}
__device__ __forceinline__ ushort_t f2bf(float f) {
  union { float f; uint_t i; } v; v.f = f;
  uint_t r = v.i + 0x7fffu + ((v.i >> 16) & 1u);
  return (ushort_t)(r >> 16);
}
// bit-level scrub: NaN/Inf -> 0
__device__ __forceinline__ float scrub(float x) {
  union { float f; uint_t i; } v; v.f = x;
  return ((v.i & 0x7f800000u) == 0x7f800000u) ? 0.f : x;
}
__device__ __forceinline__ float sclamp(float x) {
  float y = scrub(x);
  return fminf(30.f, fmaxf(-30.f, y));
}
__device__ __forceinline__ float sigm(float x) { return 1.f / (1.f + __expf(-x)); }
__device__ __forceinline__ float tanh_f(float x) {
  float t = __expf(-2.f * fabsf(x));
  float r = (1.f - t) / (1.f + t);
  return x < 0.f ? -r : r;
}
// load 8 f32, convert to bf16x8 (RNE)
__device__ __forceinline__ bf16x8 cvt8(const float* __restrict__ p) {
  f32x4 u0 = *(const f32x4*)p;
  f32x4 u1 = *(const f32x4*)(p + 4);
  bf16x8 r;
  #pragma unroll
  for (int j = 0; j < 4; ++j) { r[j] = (short)f2bf(u0[j]); r[j+4] = (short)f2bf(u1[j]); }
  return r;
}

// ---------------- zero-fill ----------------
__global__ __launch_bounds__(256) void zero_kernel(uint_t* __restrict__ p, int n32) {
  int i = blockIdx.x * 256 + threadIdx.x;
  if (i < n32) p[i] = 0;
}

// ---------------- init h2 (hi|lo packed bf16 split of f32 state), both parities ----------------
__global__ __launch_bounds__(256) void init_kernel(
    const float* __restrict__ state, uint_t* __restrict__ h2) {
  int i = blockIdx.x * 256 + threadIdx.x;   // 0..131071 over (2,128,512)
  float v = state[i];
  ushort_t hi = f2bf(v);
  ushort_t lo = f2bf(v - bf2f(hi));
  uint_t packed = ((uint_t)hi << 16) | (uint_t)lo;
  int dirp = i >> 16;          // 0/1
  int rem  = i & 65535;
  h2[(size_t)(dirp * 2 + 0) * 65536 + rem] = packed;
  h2[(size_t)(dirp * 2 + 1) * 65536 + rem] = packed;
}

// ---------------- transpose W_att (f32 1024x1024) -> WattT bf16 [j][d] ----------------
__global__ __launch_bounds__(256) void transpose_kernel(
    const float* __restrict__ W, ushort_t* __restrict__ WT) {
  __shared__ float tile[32][33];
  int bx = blockIdx.x & 31, by = blockIdx.x >> 5;
  int r0 = by * 32, c0 = bx * 32;
  int tid = threadIdx.x;
  int r = tid >> 3, c4 = (tid & 7) * 4;
  #pragma unroll
  for (int i = 0; i < 4; ++i) tile[r][c4 + i] = W[(size_t)(r0 + r) * 1024 + c0 + c4 + i];
  __syncthreads();
  int jr = tid >> 3, d4 = (tid & 7) * 4;
  #pragma unroll
  for (int i = 0; i < 4; ++i)
    WT[(size_t)(c0 + jr) * 1024 + r0 + d4 + i] = f2bf(tile[d4 + i][jr]);
}

// ---------------- the recurrent kernel (FENCE-FREE flag ring, fp32 I/O, split-bf16 MFMA) ----------------
// grid = 256 blocks (blockIdx = wg*4 + dirgroup), 512 threads (8 waves), 1 block/CU
// (112KB LDS -> 1/CU; 256 blocks co-resident -> spin-safe).
// All cross-block state (h2, flags) moves via agent-scope ATOMICS (L1/L2-bypassing,
// L3-direct) -> NO fences anywhere -> L2 stays warm for the embedding/x path.
// Producer order: __syncthreads drains vmcnt (h2 stores acked at L3) before relaxed
// flag store. Consumer order: spin -> compiler barrier -> atomic h loads.
// h_prev carried in f32 REGISTERS (thread owns its (row,col) pair across all steps).
__global__ __launch_bounds__(512, 2) void rnn_kernel(
    const int* __restrict__ tim_seq, const int* __restrict__ loc_seq,
    const float* __restrict__ emb_tim, const float* __restrict__ emb_loc,
    const float* __restrict__ state,        // [2][128][512] f32 (h0)
    uint_t* __restrict__ h2,                // [2dir][2par][128][512] u32 (hi|lo)
    const float* __restrict__ Wih_f, const float* __restrict__ Whh_f,
    const float* __restrict__ bih_f, const float* __restrict__ bhh_f,
    const float* __restrict__ Wih_b, const float* __restrict__ Whh_b,
    const float* __restrict__ bih_b, const float* __restrict__ bhh_b,
    ushort_t* __restrict__ output,          // [256][128][1024] bf16 (intermediate)
    float* __restrict__ state_out,          // d_out + 131072 : [2][128][512] f32
    uint_t* __restrict__ flags)             // [4][64]
{
  __shared__ __align__(16) ushort_t Wlds[2][2][24 * 512];  // [mat][hi/lo] 98,304 B
  __shared__ float Glds[2][64][27];                        // 13,824 B
  __shared__ float bias_l[6][8];                           //    192 B

  const int tid  = threadIdx.x;
  const int lane = tid & 63;
  const int wave = tid >> 6;
  const int bi   = blockIdx.x;
  const int dirgroup = bi & 3;
  const int wg   = bi >> 2;          // 0..63
  const int dir  = dirgroup >> 1;
  const int grp  = dirgroup & 1;
  const int b0   = grp * 64;
  const uint_t fb = (uint_t)dirgroup * 64;

  const float* Wih = dir ? Wih_b : Wih_f;
  const float* Whh = dir ? Whh_b : Whh_f;
  const float* bih = dir ? bih_b : bih_f;
  const float* bhh = dir ? bhh_b : bhh_f;

  // stage weight slices (f32 -> hi/lo bf16) into LDS, XOR-swizzled k per gate row
  for (int c = tid; c < 3072; c += 512) {     // 2 matrices * 24 rows * 64 chunks
    int m = c >= 1536 ? 1 : 0;
    int cc = c - m * 1536;
    int gcl = cc >> 6;                        // 0..23 local gate row
    int k8  = (cc & 63) << 3;                 // 0..504
    int grow = (gcl >> 3) * 512 + wg * 8 + (gcl & 7);
    const float* src = (m ? Whh : Wih) + (size_t)grow * 512 + k8;
    f32x4 u0 = *(const f32x4*)src;
    f32x4 u1 = *(const f32x4*)(src + 4);
    bf16x8 hi8, lo8;
    #pragma unroll
    for (int j = 0; j < 8; ++j) {
      float v = j < 4 ? u0[j] : u1[j - 4];
      ushort_t h = f2bf(v);
      hi8[j] = (short)h;
      lo8[j] = (short)f2bf(v - bf2f(h));
    }
    int dst = gcl * 512 + (k8 ^ ((gcl & 7) << 3));
    *(bf16x8*)&Wlds[m][0][dst] = hi8;
    *(bf16x8*)&Wlds[m][1][dst] = lo8;
  }
  if (tid < 48) {
    int m  = tid / 24;                 // 0: bih, 1: bhh
    int gg = (tid % 24) / 8;           // gate r/z/n
    int c  = tid & 7;
    const float* bb = m ? bhh : bih;
    bias_l[m * 3 + gg][c] = bb[gg * 512 + wg * 8 + c];
  }

  // h_prev registers for the elementwise role (tids 0..255)
  float hp_reg[2];
  if (tid < 256) {
    int row = tid >> 2;
    int c0  = (tid & 3) * 2;
    f32x2 s0 = *(const f32x2*)&state[(size_t)dir * 65536 + (size_t)(b0 + row) * 512 +
                                     wg * 8 + c0];
    hp_reg[0] = s0[0];
    hp_reg[1] = s0[1];
  }
  __syncthreads();

  const int m     = wave >> 2;         // 0: x-GEMM, 1: h-GEMM
  const int row0  = (wave & 3) * 16;   // row-tile base (0..48)
  const int rlane = lane & 15;
  const int kbase = (lane >> 4) * 8;

  for (int t = 0; t < 256; ++t) {
    const int td  = dir ? (255 - t) : t;
    const int par = t & 1;

    if (m == 0) {
      f32x4 acc[2][2];                 // [ct][Whi/Wlo]
      #pragma unroll
      for (int a = 0; a < 2; ++a)
        #pragma unroll
        for (int b = 0; b < 2; ++b) acc[a][b] = (f32x4){0.f, 0.f, 0.f, 0.f};
      const int arow = b0 + row0 + rlane;
      const int ti = tim_seq[td * 128 + arow];
      const int li = loc_seq[td * 128 + arow];
      const float* tA = emb_tim + (size_t)ti * 256;
      const float* lA = emb_loc + (size_t)li * 256;
      #pragma unroll
      for (int kk = 0; kk < 16; ++kk) {
        int k = kk * 32 + kbase;
        bf16x8 a = (kk < 8) ? cvt8(tA + k) : cvt8(lA + (k - 256));
        #pragma unroll
        for (int ct = 0; ct < 2; ++ct) {
          int gcl = ct * 8 + rlane;    // overlapping tiles: rows 0-15 / 8-23
          int off = gcl * 512 + (k ^ ((gcl & 7) << 3));
          bf16x8 bh = *(const bf16x8*)&Wlds[0][0][off];
          bf16x8 bl = *(const bf16x8*)&Wlds[0][1][off];
          acc[ct][0] = __builtin_amdgcn_mfma_f32_16x16x32_bf16(a, bh, acc[ct][0], 0, 0, 0);
          acc[ct][1] = __builtin_amdgcn_mfma_f32_16x16x32_bf16(a, bl, acc[ct][1], 0, 0, 0);
        }
      }
      #pragma unroll
      for (int ct = 0; ct < 2; ++ct) {
        int gcol = ct * 8 + rlane;
        int r = row0 + (lane >> 4) * 4;
        if (ct == 0 || rlane >= 8) {
          #pragma unroll
          for (int q = 0; q < 4; ++q)
            Glds[0][r + q][gcol] = acc[ct][0][q] + acc[ct][1][q];
        }
      }
    } else {
      // wait for all 64 producer WGs of this dirgroup to reach step t
      while (__hip_atomic_load(&flags[fb + lane], __ATOMIC_RELAXED,
                               __HIP_MEMORY_SCOPE_AGENT) < (uint_t)t) {
        __builtin_amdgcn_s_sleep(2);
      }
      asm volatile("" ::: "memory");   // compiler barrier: no hoisting of h loads

      f32x4 acc[2][3];                 // [ct][hh, lh, hl]
      #pragma unroll
      for (int a = 0; a < 2; ++a)
        #pragma unroll
        for (int b = 0; b < 3; ++b) acc[a][b] = (f32x4){0.f, 0.f, 0.f, 0.f};
      const u64* hrow = (const u64*)(h2 + (size_t)(dir * 2 + par) * 65536 +
                                     (size_t)(b0 + row0 + rlane) * 512);
      #pragma unroll
      for (int kk = 0; kk < 16; ++kk) {
        int k = kk * 32 + kbase;       // u32 index; /2 -> u64 index
        u64 q0 = __hip_atomic_load(hrow + (k >> 1),     __ATOMIC_RELAXED,
                                   __HIP_MEMORY_SCOPE_AGENT);
        u64 q1 = __hip_atomic_load(hrow + (k >> 1) + 1, __ATOMIC_RELAXED,
                                   __HIP_MEMORY_SCOPE_AGENT);
        u64 q2 = __hip_atomic_load(hrow + (k >> 1) + 2, __ATOMIC_RELAXED,
                                   __HIP_MEMORY_SCOPE_AGENT);
        u64 q3 = __hip_atomic_load(hrow + (k >> 1) + 3, __ATOMIC_RELAXED,
                                   __HIP_MEMORY_SCOPE_AGENT);
        uint_t w[8] = { (uint_t)q0, (uint_t)(q0 >> 32), (uint_t)q1, (uint_t)(q1 >> 32),
                        (uint_t)q2, (uint_t)(q2 >> 32), (uint_t)q3, (uint_t)(q3 >> 32) };
        bf16x8 ahi, alo;
        #pragma unroll
        for (int j = 0; j < 8; ++j) {
          ahi[j] = (short)(w[j] >> 16);
          alo[j] = (short)(w[j] & 0xffffu);
        }
        #pragma unroll
        for (int ct = 0; ct < 2; ++ct) {
          int gcl = ct * 8 + rlane;
          int off = gcl * 512 + (k ^ ((gcl & 7) << 3));
          bf16x8 bh = *(const bf16x8*)&Wlds[1][0][off];
          bf16x8 bl = *(const bf16x8*)&Wlds[1][1][off];
          acc[ct][0] = __builtin_amdgcn_mfma_f32_16x16x32_bf16(ahi, bh, acc[ct][0], 0, 0, 0);
          acc[ct][1] = __builtin_amdgcn_mfma_f32_16x16x32_bf16(alo, bh, acc[ct][1], 0, 0, 0);
          acc[ct][2] = __builtin_amdgcn_mfma_f32_16x16x32_bf16(ahi, bl, acc[ct][2], 0, 0, 0);
        }
      }
      #pragma unroll
      for (int ct = 0; ct < 2; ++ct) {
        int gcol = ct * 8 + rlane;
        int r = row0 + (lane >> 4) * 4;
        if (ct == 0 || rlane >= 8) {
          #pragma unroll
          for (int q = 0; q < 4; ++q)
            Glds[1][r + q][gcol] = acc[ct][0][q] + acc[ct][1][q] + acc[ct][2][q];
        }
      }
    }
    __syncthreads();

    // elementwise: 64 rows x 4 col-pairs = 256 items, one per thread; h_prev in regs
    if (tid < 256) {
      int row = tid >> 2;
      int cp  = tid & 3;
      int c0  = cp * 2;
      uint_t packed_out = 0;
      size_t hnew = (size_t)(dir * 2 + (par ^ 1)) * 65536 + (size_t)(b0 + row) * 512 + wg * 8;
      #pragma unroll
      for (int j = 0; j < 2; ++j) {
        int c = c0 + j;
        float gxr = sclamp(Glds[0][row][c]      + bias_l[0][c]);
        float gxz = sclamp(Glds[0][row][8 + c]  + bias_l[1][c]);
        float gxn = sclamp(Glds[0][row][16 + c] + bias_l[2][c]);
        float ghr = sclamp(Glds[1][row][c]      + bias_l[3][c]);
        float ghz = sclamp(Glds[1][row][8 + c]  + bias_l[4][c]);
        float ghn = sclamp(Glds[1][row][16 + c] + bias_l[5][c]);
        float r = sigm(gxr + ghr);
        float z = sigm(gxz + ghz);
        float n = tanh_f(gxn + r * ghn);
        float hn = (1.f - z) * n + z * hp_reg[j];
        hp_reg[j] = hn;
        ushort_t hh = f2bf(hn);
        ushort_t hl = f2bf(hn - bf2f(hh));
        __hip_atomic_store(&h2[hnew + c], ((uint_t)hh << 16) | (uint_t)hl,
                           __ATOMIC_RELAXED, __HIP_MEMORY_SCOPE_AGENT);
        packed_out |= ((uint_t)hh) << (16 * j);
      }
      *(uint_t*)&output[(size_t)td * 131072 + (size_t)(b0 + row) * 1024 +
                        dir * 512 + wg * 8 + c0] = packed_out;
      if (t == 255) {
        *(f32x2*)&state_out[(size_t)dir * 65536 + (size_t)(b0 + row) * 512 +
                            wg * 8 + c0] = (f32x2){hp_reg[0], hp_reg[1]};
      }
    }
    __syncthreads();   // drains vmcnt: h2 stores acked at L3 before flag release
    if (t < 255 && tid == 0) {
      __hip_atomic_store(&flags[fb + wg], (uint_t)(t + 1), __ATOMIC_RELAXED,
                         __HIP_MEMORY_SCOPE_AGENT);
    }
  }
}

// ---------------- fused attention scores: scores[b][t] = w_proj . tanh(out @ W_att + b_att) ----------------
__global__ __launch_bounds__(256) void score_kernel(
    const ushort_t* __restrict__ output,   // [32768][1024] bf16
    const ushort_t* __restrict__ WattT,    // [1024][1024] bf16 (j, d)
    const float* __restrict__ b_att,       // [1024] f32
    const float* __restrict__ w_proj,      // [1024] f32
    float* __restrict__ scores)            // [128][256]
{
  __shared__ __align__(16) ushort_t bst[2][128][72];
  __shared__ float scl[128];
  const int tid = threadIdx.x, lane = tid & 63, wave = tid >> 6;
  const int tb0 = blockIdx.x * 128;
  if (tid < 128) scl[tid] = 0.f;
  __syncthreads();

  const int rlane = lane & 15;
  const int kbase = (lane >> 4) * 8;
  const int sjrow = tid >> 2;
  const int sq8   = (tid & 3) * 8;

  for (int jc = 0; jc < 8; ++jc) {
    f32x4 acc[2][8];
    #pragma unroll
    for (int rt = 0; rt < 2; ++rt)
      #pragma unroll
      for (int ct = 0; ct < 8; ++ct) acc[rt][ct] = (f32x4){0.f, 0.f, 0.f, 0.f};

    {
      const size_t base = (size_t)(jc * 128) * 1024 + sq8;
      *(bf16x8*)&bst[0][sjrow][sq8] = *(const bf16x8*)(WattT + base + (size_t)sjrow * 1024);
      *(bf16x8*)&bst[0][sjrow + 64][sq8] = *(const bf16x8*)(WattT + base + (size_t)(sjrow + 64) * 1024);
    }
    __syncthreads();

    for (int kc = 0; kc < 32; ++kc) {
      if (kc < 31) {
        const size_t base = (size_t)(jc * 128) * 1024 + (size_t)(kc + 1) * 32 + sq8;
        *(bf16x8*)&bst[(kc + 1) & 1][sjrow][sq8] =
            *(const bf16x8*)(WattT + base + (size_t)sjrow * 1024);
        *(bf16x8*)&bst[(kc + 1) & 1][sjrow + 64][sq8] =
            *(const bf16x8*)(WattT + base + (size_t)(sjrow + 64) * 1024);
      }
      int r0 = wave * 32 + rlane;
      int k = kc * 32 + kbase;
      bf16x8 a0 = *(const bf16x8*)(output + (size_t)(tb0 + r0) * 1024 + k);
      bf16x8 a1 = *(const bf16x8*)(output + (size_t)(tb0 + r0 + 16) * 1024 + k);
      int buf = kc & 1;
      #pragma unroll
      for (int ct = 0; ct < 8; ++ct) {
        bf16x8 b = *(const bf16x8*)&bst[buf][ct * 16 + rlane][kbase];
        acc[0][ct] = __builtin_amdgcn_mfma_f32_16x16x32_bf16(a0, b, acc[0][ct], 0, 0, 0);
        acc[1][ct] = __builtin_amdgcn_mfma_f32_16x16x32_bf16(a1, b, acc[1][ct], 0, 0, 0);
      }
      __syncthreads();
    }

    float s[2][4] = {{0.f, 0.f, 0.f, 0.f}, {0.f, 0.f, 0.f, 0.f}};
    #pragma unroll
    for (int ct = 0; ct < 8; ++ct) {
      int j = jc * 128 + ct * 16 + rlane;
      float bv = b_att[j];
      float wv = w_proj[j];
      #pragma unroll
      for (int rt = 0; rt < 2; ++rt)
        #pragma unroll
        for (int q = 0; q < 4; ++q)
          s[rt][q] += tanh_f(sclamp(acc[rt][ct][q] + bv)) * wv;
    }
    #pragma unroll
    for (int rt = 0; rt < 2; ++rt)
      #pragma unroll
      for (int q = 0; q < 4; ++q) {
        float v = s[rt][q];
        v += __shfl_xor(v, 1, 64);
        v += __shfl_xor(v, 2, 64);
        v += __shfl_xor(v, 4, 64);
        v += __shfl_xor(v, 8, 64);
        if ((lane & 15) == 0)
          scl[wave * 32 + rt * 16 + (lane >> 4) * 4 + q] += v;
      }
  }
  __syncthreads();
  if (tid < 128) {
    int tb = tb0 + tid;
    scores[(size_t)(tb & 127) * 256 + (tb >> 7)] = scrub(scl[tid]);
  }
}

// ---------------- softmax over t per batch row (f32 out) ----------------
__global__ __launch_bounds__(256) void softmax_kernel(
    const float* __restrict__ scores, float* __restrict__ attn_out) {
  __shared__ float red[4];
  int b = blockIdx.x, tid = threadIdx.x, lane = tid & 63, wave = tid >> 6;
  float v = scrub(scores[(size_t)b * 256 + tid]);
  float mx = v;
  #pragma unroll
  for (int o = 1; o < 64; o <<= 1) mx = fmaxf(mx, __shfl_xor(mx, o, 64));
  if (lane == 0) red[wave] = mx;
  __syncthreads();
  mx = fmaxf(fmaxf(red[0], red[1]), fmaxf(red[2], red[3]));
  float e = __expf(v - mx);
  float s = e;
  #pragma unroll
  for (int o = 1; o < 64; o <<= 1) s += __shfl_xor(s, o, 64);
  __syncthreads();
  if (lane == 0) red[wave] = s;
  __syncthreads();
  s = red[0] + red[1] + red[2] + red[3];
  attn_out[(size_t)b * 256 + tid] = e / s;
}

// ---------------- pooled[b][d] = sum_t attn[b][t]*output[t][b][d] (f32 out) ----------------
__global__ __launch_bounds__(256) void pool_kernel(
    const float* __restrict__ attnw, const ushort_t* __restrict__ output,
    float* __restrict__ pooled) {
  __shared__ float at[256];
  int bi = blockIdx.x;
  int b = bi >> 1, half = bi & 1;
  int tid = threadIdx.x;
  at[tid] = scrub(attnw[(size_t)b * 256 + tid]);
  __syncthreads();
  int d0 = half * 512 + tid * 2;
  float a0 = 0.f, a1 = 0.f;
  for (int t = 0; t < 256; ++t) {
    uint_t u = *(const uint_t*)&output[(size_t)t * 131072 + (size_t)b * 1024 + d0];
    float w = at[t];
    a0 += w * scrub(bf2f((ushort_t)(u & 0xffffu)));
    a1 += w * scrub(bf2f((ushort_t)(u >> 16)));
  }
  *(f32x2*)&pooled[(size_t)b * 1024 + d0] = (f32x2){a0, a1};
}

extern "C" void kernel_launch(void* const* d_in, const int* in_sizes, int n_in,
                              void* d_out, int out_size, void* d_ws, size_t ws_size,
                              hipStream_t stream) {
  (void)in_sizes; (void)n_in; (void)out_size;
  const int*   tim_seq = (const int*)d_in[0];
  const int*   loc_seq = (const int*)d_in[1];
  const float* state   = (const float*)d_in[2];
  const float* emb_tim = (const float*)d_in[3];
  const float* emb_loc = (const float*)d_in[4];
  const float* Wih_f   = (const float*)d_in[5];
  const float* Whh_f   = (const float*)d_in[6];
  const float* bih_f   = (const float*)d_in[7];
  const float* bhh_f   = (const float*)d_in[8];
  const float* Wih_b   = (const float*)d_in[9];
  const float* Whh_b   = (const float*)d_in[10];
  const float* bih_b   = (const float*)d_in[11];
  const float* bhh_b   = (const float*)d_in[12];
  const float* W_att   = (const float*)d_in[13];
  const float* b_att   = (const float*)d_in[14];
  const float* w_proj  = (const float*)d_in[15];
  float* out = (float*)d_out;   // [pooled 131072][state 131072][attn 32768] f32

  // Workspace layout (~70.5 MB; verified available)
  char* ws = (char*)d_ws;
  float*    scores = (float*)   (ws);                   //   131,072 B
  uint_t*   flags  = (uint_t*)  (ws + 131072);          //     1,024 B
  uint_t*   h2     = (uint_t*)  (ws + 132096);          // 1,048,576 B
  ushort_t* WattT  = (ushort_t*)(ws + 1180672);         // 2,097,152 B
  ushort_t* output = (ushort_t*)(ws + 3277824);         // 67,108,864 B
  const size_t NEED = 3277824 + 67108864;
  if (ws_size < NEED) return;

  zero_kernel<<<1, 256, 0, stream>>>(flags, 256);   // only flags need zeroing

  init_kernel<<<512, 256, 0, stream>>>(state, h2);
  transpose_kernel<<<1024, 256, 0, stream>>>(W_att, WattT);

  rnn_kernel<<<256, 512, 0, stream>>>(tim_seq, loc_seq, emb_tim, emb_loc, state,
                                      h2,
                                      Wih_f, Whh_f, bih_f, bhh_f,
                                      Wih_b, Whh_b, bih_b, bhh_b,
                                      output, out + 131072, flags);

  score_kernel<<<256, 256, 0, stream>>>(output, WattT, b_att, w_proj, scores);
  softmax_kernel<<<128, 256, 0, stream>>>(scores, out + 262144);
  pool_kernel<<<256, 256, 0, stream>>>(out + 262144, output, out);
}